// Round 3
// baseline (551.469 us; speedup 1.0000x reference)
//
#include <hip/hip_runtime.h>
#include <math.h>

// ---------------------------------------------------------------------------
// SelfAttention R3: k_attn rebuilt barrier-free — K/V fragments read directly
// global->VGPR (B-operand rows are coalesced; 32KB tile fits L1; 4x wave reuse
// hits L1), Ps stays wave-private in LDS (no barrier needed). Zero
// __syncthreads in the key loop -> compiler can interleave MFMA with loads
// using fine-grained vmcnt instead of full barrier drains.
// GEMMs (qkv/proj) kept at the m97-structure plateau (~937 TF measured R2).
// ---------------------------------------------------------------------------

typedef __bf16 bf16_t;
typedef __bf16 bf16x8 __attribute__((ext_vector_type(8)));
typedef __bf16 bf16x4v __attribute__((ext_vector_type(4)));
typedef float  f32x4  __attribute__((ext_vector_type(4)));

#define B_  2
#define T_  2048
#define C_  2048
#define SLICE_ ((size_t)B_ * T_ * C_)  // 8388608

__device__ __forceinline__ void glds16(const void* g, void* l) {
  __builtin_amdgcn_global_load_lds(
      (__attribute__((address_space(1))) void*)(void*)(const_cast<void*>(g)),
      (__attribute__((address_space(3))) void*)(l), 16, 0, 0);
}

// ------------------- fused f32 -> bf16 pack (x | w_qkv | w_proj) -----------
// outputs are contiguous in workspace: xb(2097152 f4) wqkvb(3145728) wprojb(1048576)
__global__ __launch_bounds__(256) void k_cvt_all(
    const float4* __restrict__ x, const float4* __restrict__ wq,
    const float4* __restrict__ wp, bf16x4v* __restrict__ out) {
  int i = blockIdx.x * 256 + threadIdx.x;  // 6291456 total
  float4 v;
  if (i < 2097152) v = x[i];
  else if (i < 5242880) v = wq[i - 2097152];
  else v = wp[i - 5242880];
  bf16x4v o;
  o[0] = (bf16_t)v.x; o[1] = (bf16_t)v.y; o[2] = (bf16_t)v.z; o[3] = (bf16_t)v.w;
  out[i] = o;
}

// ------------------------- rope cos/sin table ------------------------------
__global__ __launch_bounds__(256) void k_tab(float2* __restrict__ tab) {
  int i = blockIdx.x * 256 + threadIdx.x;  // 131072
  int t = i >> 6, j = i & 63;
  float thf = (float)pow(10000.0, -(double)(2 * j) / 128.0);
  float angf = (float)t * thf;
  double a = (double)angf;
  tab[i] = make_float2((float)cos(a), (float)sin(a));
}

// ------------------------- QKV GEMM + RoPE epilogue ------------------------
__global__ __launch_bounds__(256, 2) void k_qkv(
    const bf16_t* __restrict__ X, const bf16_t* __restrict__ W,
    const float2* __restrict__ tab,
    bf16_t* __restrict__ qb, bf16_t* __restrict__ kb, bf16_t* __restrict__ vtb,
    float* __restrict__ kout, float* __restrict__ vout) {
  const int K = 2048;
  __shared__ alignas(16) bf16_t smem[17408];
  bf16_t* As = smem;
  bf16_t* Bs = smem + 8192;
  const int tid = threadIdx.x;
  const int lane = tid & 63, wv = tid >> 6;
  const int wm = wv >> 1, wn = wv & 1;
  const int q4 = lane >> 4, l16 = lane & 15;
  const int m0 = blockIdx.x * 128, n0 = blockIdx.y * 128;

  const bf16_t* Ab = X + (size_t)m0 * K;
  const bf16_t* Wb = W + (size_t)n0 * K;

  f32x4 zero4 = {0.f, 0.f, 0.f, 0.f};
  f32x4 acc[4][4];
#pragma unroll
  for (int i = 0; i < 4; ++i)
#pragma unroll
    for (int j = 0; j < 4; ++j) acc[i][j] = zero4;

  for (int k0 = 0; k0 < K; k0 += 64) {
    __syncthreads();
#pragma unroll
    for (int i = 0; i < 4; ++i) {
      int ci = i * 256 + tid;
      glds16(Ab + (size_t)(ci >> 3) * K + k0 + (((ci & 7) ^ ((ci >> 3) & 7)) << 3),
             &As[(i * 256 + wv * 64) * 8]);
    }
#pragma unroll
    for (int i = 0; i < 4; ++i) {
      int ci = i * 256 + tid;
      glds16(Wb + (size_t)(ci >> 3) * K + k0 + (((ci & 7) ^ ((ci >> 3) & 7)) << 3),
             &Bs[(i * 256 + wv * 64) * 8]);
    }
    __syncthreads();
#pragma unroll
    for (int kk = 0; kk < 2; ++kk) {
      bf16x8 afrag[4], bfrag[4];
#pragma unroll
      for (int mf = 0; mf < 4; ++mf)
        afrag[mf] = *(const bf16x8*)&As[(wm * 64 + mf * 16 + l16) * 64 +
                                        ((((kk << 2) | q4) ^ (l16 & 7)) << 3)];
#pragma unroll
      for (int nf = 0; nf < 4; ++nf)
        bfrag[nf] = *(const bf16x8*)&Bs[(wn * 64 + nf * 16 + l16) * 64 +
                                        ((((kk << 2) | q4) ^ (l16 & 7)) << 3)];
#pragma unroll
      for (int mf = 0; mf < 4; ++mf)
#pragma unroll
        for (int nf = 0; nf < 4; ++nf)
          acc[mf][nf] = __builtin_amdgcn_mfma_f32_16x16x32_bf16(
              afrag[mf], bfrag[nf], acc[mf][nf], 0, 0, 0);
    }
  }

  __syncthreads();
  const int sec = n0 >> 11;
  const int t0 = m0 & 2047, bb = m0 >> 11, h = (n0 & 2047) >> 7;

  if (sec < 2) {
#pragma unroll
    for (int mf = 0; mf < 4; ++mf)
#pragma unroll
      for (int nf = 0; nf < 4; ++nf)
#pragma unroll
        for (int r = 0; r < 4; ++r) {
          int ml = wm * 64 + mf * 16 + q4 * 4 + r;
          int d = wn * 64 + nf * 16 + l16;
          float val = acc[mf][nf][r];
          float partner = __shfl_xor(val, 1);
          float2 cs = tab[(t0 + ml) * 64 + (d >> 1)];
          float rv = (d & 1) ? (val * cs.x + partner * cs.y)
                             : (val * cs.x - partner * cs.y);
          if (sec == 0) rv *= 0.08838834764831845f;
          else kout[(size_t)(m0 + ml) * 2048 + h * 128 + d] = val;
          smem[ml * 136 + d] = (bf16_t)rv;
        }
    __syncthreads();
    bf16_t* dst = (sec == 0 ? qb : kb);
    size_t gbase = ((size_t)(bb * 16 + h) * 2048 + t0) * 128;
#pragma unroll
    for (int i = 0; i < 8; ++i) {
      int ci = i * 256 + tid, ml = ci >> 4, cc = (ci & 15) * 8;
      *(bf16x8*)(dst + gbase + (size_t)ml * 128 + cc) =
          *(const bf16x8*)&smem[ml * 136 + cc];
    }
  } else {
#pragma unroll
    for (int mf = 0; mf < 4; ++mf)
#pragma unroll
      for (int nf = 0; nf < 4; ++nf)
#pragma unroll
        for (int r = 0; r < 4; ++r) {
          int ml = wm * 64 + mf * 16 + q4 * 4 + r;
          int d = wn * 64 + nf * 16 + l16;
          float val = acc[mf][nf][r];
          vout[((size_t)(bb * 16 + h) * 2048 + t0 + ml) * 128 + d] = val;
          smem[d * 136 + ml] = (bf16_t)val;
        }
    __syncthreads();
#pragma unroll
    for (int i = 0; i < 8; ++i) {
      int ci = i * 256 + tid, dr = ci >> 4, cc = (ci & 15) * 8;
      *(bf16x8*)(vtb + ((size_t)((bb * 16 + h) * 128 + dr)) * 2048 + t0 + cc) =
          *(const bf16x8*)&smem[dr * 136 + cc];
    }
  }
}

// ------------------------- flash attention (barrier-free) ------------------
// block = (b,h) x 128 queries, 4 waves x 32 queries. KT=64.
// K/V fragments read directly from global (L1-cached, 4x wave reuse).
// Ps wave-private in LDS. No __syncthreads anywhere.
__global__ __launch_bounds__(256, 2) void k_attn(
    const bf16_t* __restrict__ qb, const bf16_t* __restrict__ kb,
    const bf16_t* __restrict__ vtb, bf16_t* __restrict__ ob) {
  __shared__ alignas(16) bf16_t Ps[128 * 80];

  const int tid = threadIdx.x;
  const int lane = tid & 63, wv = tid >> 6;
  const int q4 = lane >> 4, l16 = lane & 15;
  const int bh = blockIdx.x & 31;         // all 16 q-tiles of a head: same XCD
  const int q0 = (blockIdx.x >> 5) * 128;

  const bf16_t* Qg = qb + (size_t)bh * T_ * 128 + (size_t)q0 * 128;
  const bf16_t* Kg = kb + (size_t)bh * T_ * 128;
  const bf16_t* Vg = vtb + (size_t)bh * 128 * T_;

  bf16x8 qa[2][4];
#pragma unroll
  for (int mf = 0; mf < 2; ++mf)
#pragma unroll
    for (int kf = 0; kf < 4; ++kf)
      qa[mf][kf] = *(const bf16x8*)(Qg + (size_t)(wv * 32 + mf * 16 + l16) * 128 +
                                    kf * 32 + q4 * 8);

  f32x4 zero4 = {0.f, 0.f, 0.f, 0.f};
  float lrow[2][4];
  f32x4 oacc[2][8];
#pragma unroll
  for (int mf = 0; mf < 2; ++mf) {
#pragma unroll
    for (int r = 0; r < 4; ++r) lrow[mf][r] = 0.f;
#pragma unroll
    for (int nf = 0; nf < 8; ++nf) oacc[mf][nf] = zero4;
  }

  for (int key0 = 0; key0 < T_; key0 += 64) {
    // S = Q K^T; K frags straight from global (rows of kb, coalesced)
    f32x4 sacc[2][4];
#pragma unroll
    for (int mf = 0; mf < 2; ++mf)
#pragma unroll
      for (int nf = 0; nf < 4; ++nf) sacc[mf][nf] = zero4;
#pragma unroll
    for (int kf = 0; kf < 4; ++kf) {
      bf16x8 bfrag[4];
#pragma unroll
      for (int nf = 0; nf < 4; ++nf)
        bfrag[nf] = *(const bf16x8*)(Kg + (size_t)(key0 + nf * 16 + l16) * 128 +
                                     kf * 32 + q4 * 8);
#pragma unroll
      for (int mf = 0; mf < 2; ++mf)
#pragma unroll
        for (int nf = 0; nf < 4; ++nf)
          sacc[mf][nf] = __builtin_amdgcn_mfma_f32_16x16x32_bf16(
              qa[mf][kf], bfrag[nf], sacc[mf][nf], 0, 0, 0);
    }

    // exp + P to LDS (wave-private rows; in-wave LDS ordering, no barrier)
#pragma unroll
    for (int mf = 0; mf < 2; ++mf) {
#pragma unroll
      for (int r = 0; r < 4; ++r) {
        float p0 = __expf(sacc[mf][0][r]);
        float p1 = __expf(sacc[mf][1][r]);
        float p2 = __expf(sacc[mf][2][r]);
        float p3 = __expf(sacc[mf][3][r]);
        int prow = wv * 32 + mf * 16 + q4 * 4 + r;
        Ps[prow * 80 + 0 + l16]  = (bf16_t)p0;
        Ps[prow * 80 + 16 + l16] = (bf16_t)p1;
        Ps[prow * 80 + 32 + l16] = (bf16_t)p2;
        Ps[prow * 80 + 48 + l16] = (bf16_t)p3;
        lrow[mf][r] += (p0 + p1) + (p2 + p3);
      }
    }

    // O += P V; V frags straight from global (rows of vtb, coalesced)
#pragma unroll
    for (int kf2 = 0; kf2 < 2; ++kf2) {
      bf16x8 pa[2], vb[8];
#pragma unroll
      for (int mf = 0; mf < 2; ++mf)
        pa[mf] = *(const bf16x8*)&Ps[(wv * 32 + mf * 16 + l16) * 80 +
                                     kf2 * 32 + q4 * 8];
#pragma unroll
      for (int nf = 0; nf < 8; ++nf)
        vb[nf] = *(const bf16x8*)(Vg + (size_t)(nf * 16 + l16) * 2048 + key0 +
                                  kf2 * 32 + q4 * 8);
#pragma unroll
      for (int mf = 0; mf < 2; ++mf)
#pragma unroll
        for (int nf = 0; nf < 8; ++nf)
          oacc[mf][nf] = __builtin_amdgcn_mfma_f32_16x16x32_bf16(
              pa[mf], vb[nf], oacc[mf][nf], 0, 0, 0);
    }
  }

  const int b = bh >> 4, h = bh & 15;
#pragma unroll
  for (int mf = 0; mf < 2; ++mf) {
#pragma unroll
    for (int r = 0; r < 4; ++r) {
      float l = lrow[mf][r];
      l += __shfl_xor(l, 1);
      l += __shfl_xor(l, 2);
      l += __shfl_xor(l, 4);
      l += __shfl_xor(l, 8);
      float inv = 1.f / l;
      int t = q0 + wv * 32 + mf * 16 + q4 * 4 + r;
      size_t base = ((size_t)b * 2048 + t) * 2048 + h * 128;
#pragma unroll
      for (int nf = 0; nf < 8; ++nf)
        ob[base + nf * 16 + l16] = (bf16_t)(oacc[mf][nf][r] * inv);
    }
  }
}

// ------------------------- projection GEMM ---------------------------------
__global__ __launch_bounds__(256, 2) void k_proj(
    const bf16_t* __restrict__ O, const bf16_t* __restrict__ Wp,
    float* __restrict__ Y) {
  const int K = 2048;
  __shared__ alignas(16) bf16_t As[128 * 64];
  __shared__ alignas(16) bf16_t Bs[128 * 64];
  const int tid = threadIdx.x;
  const int lane = tid & 63, wv = tid >> 6;
  const int wm = wv >> 1, wn = wv & 1;
  const int q4 = lane >> 4, l16 = lane & 15;
  const int m0 = blockIdx.x * 128, n0 = blockIdx.y * 128;

  const bf16_t* Ab = O + (size_t)m0 * K;
  const bf16_t* Wb = Wp + (size_t)n0 * K;

  f32x4 zero4 = {0.f, 0.f, 0.f, 0.f};
  f32x4 acc[4][4];
#pragma unroll
  for (int i = 0; i < 4; ++i)
#pragma unroll
    for (int j = 0; j < 4; ++j) acc[i][j] = zero4;

  for (int k0 = 0; k0 < K; k0 += 64) {
    __syncthreads();
#pragma unroll
    for (int i = 0; i < 4; ++i) {
      int ci = i * 256 + tid;
      glds16(Ab + (size_t)(ci >> 3) * K + k0 + (((ci & 7) ^ ((ci >> 3) & 7)) << 3),
             &As[(i * 256 + wv * 64) * 8]);
    }
#pragma unroll
    for (int i = 0; i < 4; ++i) {
      int ci = i * 256 + tid;
      glds16(Wb + (size_t)(ci >> 3) * K + k0 + (((ci & 7) ^ ((ci >> 3) & 7)) << 3),
             &Bs[(i * 256 + wv * 64) * 8]);
    }
    __syncthreads();
#pragma unroll
    for (int kk = 0; kk < 2; ++kk) {
      bf16x8 afrag[4], bfrag[4];
#pragma unroll
      for (int mf = 0; mf < 4; ++mf)
        afrag[mf] = *(const bf16x8*)&As[(wm * 64 + mf * 16 + l16) * 64 +
                                        ((((kk << 2) | q4) ^ (l16 & 7)) << 3)];
#pragma unroll
      for (int nf = 0; nf < 4; ++nf)
        bfrag[nf] = *(const bf16x8*)&Bs[(wn * 64 + nf * 16 + l16) * 64 +
                                        ((((kk << 2) | q4) ^ (l16 & 7)) << 3)];
#pragma unroll
      for (int mf = 0; mf < 4; ++mf)
#pragma unroll
        for (int nf = 0; nf < 4; ++nf)
          acc[mf][nf] = __builtin_amdgcn_mfma_f32_16x16x32_bf16(
              afrag[mf], bfrag[nf], acc[mf][nf], 0, 0, 0);
    }
  }
#pragma unroll
  for (int mf = 0; mf < 4; ++mf)
#pragma unroll
    for (int nf = 0; nf < 4; ++nf)
#pragma unroll
      for (int r = 0; r < 4; ++r) {
        int m = m0 + wm * 64 + mf * 16 + q4 * 4 + r;
        int n = n0 + wn * 64 + nf * 16 + l16;
        Y[(size_t)m * 2048 + n] = acc[mf][nf][r];
      }
}

// ------------------------- launch ------------------------------------------
extern "C" void kernel_launch(void* const* d_in, const int* in_sizes, int n_in,
                              void* d_out, int out_size, void* d_ws, size_t ws_size,
                              hipStream_t stream) {
  const float* x = (const float*)d_in[0];
  const float* wqkv = (const float*)d_in[1];
  const float* wproj = (const float*)d_in[2];

  float* y = (float*)d_out;
  float* kout = y + SLICE_;
  float* vout = y + 2 * SLICE_;

  char* w = (char*)d_ws;
  bf16_t* xb = (bf16_t*)w;      w += SLICE_ * 2;
  bf16_t* wqkvb = (bf16_t*)w;   w += (size_t)12582912 * 2;
  bf16_t* wprojb = (bf16_t*)w;  w += (size_t)4194304 * 2;
  bf16_t* qb = (bf16_t*)w;      w += SLICE_ * 2;
  bf16_t* kb = (bf16_t*)w;      w += SLICE_ * 2;
  bf16_t* vtb = (bf16_t*)w;     w += SLICE_ * 2;
  bf16_t* ob = (bf16_t*)w;      w += SLICE_ * 2;
  float2* tab = (float2*)w;     w += (size_t)131072 * 8;
  (void)ws_size; (void)in_sizes; (void)n_in; (void)out_size;

  k_cvt_all<<<24576, 256, 0, stream>>>((const float4*)x, (const float4*)wqkv,
                                       (const float4*)wproj, (bf16x4v*)xb);
  k_tab<<<512, 256, 0, stream>>>(tab);

  dim3 gq(32, 48);
  k_qkv<<<gq, 256, 0, stream>>>(xb, wqkvb, tab, qb, kb, vtb, kout, vout);
  k_attn<<<512, 256, 0, stream>>>(qb, kb, vtb, ob);
  dim3 gp(32, 16);
  k_proj<<<gp, 256, 0, stream>>>(ob, wprojb, y);
}